// Round 13
// baseline (2127.278 us; speedup 1.0000x reference)
//
#include <hip/hip_runtime.h>
#include <hip/hip_fp16.h>

// FixedFreqModel: B=512, L=2048, M=256, H=64, VOCAB=64, READ_FREQ=16.
// R25 = R24 (1050us steady) restructured: TWO independent batch chains per
// wave, manually interleaved (ILP latency-hiding).
//  - R24 counters: per-wave issue occupancy ~35%; ~65% of cycles are
//    dependency-latency bubbles (dot2 chains, readlane/pkrtz, shfl, exp).
//    2 waves/CU on 4 SIMDs -> no TLP to fill them. All prior structural
//    attempts shortened ONE chain; this fills the bubbles with a second
//    INDEPENDENT chain instead.
//  - Wave handles b0=2*wg, b1=2*wg+1. Weights (W_hh, WR, G4, head, kT-fold
//    tables) shared; per-b state (h, hpu, kT/v LDS tiles, tokens, cc)
//    duplicated. GRU_STEP2 interleaves both chains per kp: 2 readlane +
//    6 dot2 on shared weight regs. Scores/v/R loops likewise interleaved.
//  - Grid 256 = 1 WG/CU (forced by 133KB LDS anyway). Per-b math is
//    bit-identical to R24 -> absmax unchanged.
// Precompute kernels unchanged from R24.

#define B_ 512
#define L_ 2048
#define M_ 256
#define H_ 64
#define C_ 128
#define F_ 16

typedef float v2f __attribute__((ext_vector_type(2)));
typedef _Float16 h2v __attribute__((ext_vector_type(2)));

#if __has_builtin(__builtin_amdgcn_fdot2)
__device__ __forceinline__ float FDOT2(h2v a, h2v b, float c) {
    return __builtin_amdgcn_fdot2(a, b, c, false);
}
#else
__device__ __forceinline__ float FDOT2(h2v a, h2v b, float c) {
    return c + (float)a[0]*(float)b[0] + (float)a[1]*(float)b[1];
}
#endif

__device__ __forceinline__ h2v bch(unsigned u) { return __builtin_bit_cast(h2v, u); }
__device__ __forceinline__ unsigned rl_u(unsigned v, int lane) {
    return (unsigned)__builtin_amdgcn_readlane((int)v, lane);
}
__device__ __forceinline__ float rl(float v, int lane) {
    return __int_as_float(__builtin_amdgcn_readlane(__float_as_int(v), lane));
}
__device__ __forceinline__ unsigned pkrtz(float a, float b) {
    auto r = __builtin_amdgcn_cvt_pkrtz(a, b);     // __fp16 ext_vector(2)
    return __builtin_bit_cast(unsigned, r);
}
__device__ __forceinline__ float dot4(float4 a, float4 b) {
    return a.x*b.x + a.y*b.y + a.z*b.z + a.w*b.w;
}
__device__ __forceinline__ float fast_rcp(float x) { return __builtin_amdgcn_rcpf(x); }
__device__ __forceinline__ float sigm(float x) { return fast_rcp(1.f + __expf(-x)); }
__device__ __forceinline__ float tanh_f(float x) {
    float e2 = __expf(-2.f * fabsf(x));
    return copysignf((1.f - e2) * fast_rcp(1.f + e2), x);
}
__device__ __forceinline__ unsigned h2rn(float a, float b) {
    __half2 h = __floats2half2_rn(a, b);
    return __builtin_bit_cast(unsigned, h);
}

// workspace offsets (bytes)
#define WS_KT    0u            // K'T2: 512 * 8192 u32 = 16 MB  [b][hh2][m]
#define WS_V     16777216u     // vT2: 512 * 8192 u32 = 16 MB  [b][o][mp]
#define WS_G4    33554432u     // 64*64 float4 = 64 KB  (a0,a1,a2,pad)
#define WS_WPHH  33619968u     // 6144 u32 = 24 KB  [(k2*3+g)*64+j]
#define WS_WR    33644544u     // 6144 u32 = 24 KB
#define WS_KQP   33669120u     // 1024 float4 = 16 KB (folded K.Q, packed)
#define WS_VWP   33685504u     // 16 KB
#define WS_KQF   33701888u     // 4096 fp32 = 16 KB (KQ scalar, pre-pack)
#define WS_BQ    33718272u     // 64 fp32 (bq = kb.Wq)
#define WS_KQV   33718528u     // 64 fp32 (kq = Kw^T qb)
#define WS_C0    33718784u     // 1 fp32 (c0 = kb.qb), padded
#define WS_CB    33719040u     // 512*256 fp32 = 512 KB (c[b][m])

// dynamic LDS layout (bytes): two per-b tiles
#define S_KT0  0u        // 32768 : K'T2 u32 [hh2=32][m=256]  (b0)
#define S_KT1  32768u    // 32768 : (b1)
#define S_V0   65536u    // 33792 : vP u32 [o=64][132]  (b0)
#define S_V1   99328u    // 33792 : (b1)
#define SMEM_BYTES 133120u

// ---------------- pack weights -----------------------------------------------
__global__ void pack_weights(const float* __restrict__ w_ih,
                             const float* __restrict__ w_hh,
                             const float* __restrict__ vw,
                             unsigned* __restrict__ WPhh2,
                             unsigned* __restrict__ WR2p,
                             float4* __restrict__ VWP)
{
    int idx = blockIdx.x * 256 + threadIdx.x;
    if (idx < 6144) {                        // WPhh2[(k2*3+g)*64+j]
        int j = idx & 63, t = idx >> 6, g = t % 3, k2 = t / 3;
        const float* s = w_hh + (g*64 + j)*64 + 2*k2;
        WPhh2[idx] = h2rn(s[0], s[1]);
    } else if (idx < 12288) {                // WR2p: retrieved half of w_ih
        int i = idx - 6144;
        int j = i & 63, t = i >> 6, g = t % 3, k2 = t / 3;
        const float* s = w_ih + (g*64 + j)*128 + 64 + 2*k2;
        WR2p[i] = h2rn(s[0], s[1]);
    } else if (idx < 13312) {                // VWP
        int i = idx - 12288;
        int j = i & 63, k4 = i >> 6;
        const float* s = vw + j*64 + 4*k4;
        VWP[i] = make_float4(s[0], s[1], s[2], s[3]);
    }
}

// ------ fold_kq: KQ[d][j] = sum_t Kw[t][d]*Wq[t][j]; bq, kq, c0 --------------
__global__ __launch_bounds__(64) void fold_kq(const float* __restrict__ kw,
                                              const float* __restrict__ qw,
                                              const float* __restrict__ kb,
                                              const float* __restrict__ qb,
                                              float* __restrict__ KQf,
                                              float* __restrict__ bqv,
                                              float* __restrict__ kqv,
                                              float* __restrict__ c0p)
{
    int d = blockIdx.x, j = threadIdx.x;
    __shared__ float kcol[64], kbs[64], qbs[64];
    kcol[j] = kw[j*64 + d];
    kbs[j]  = kb[j];
    qbs[j]  = qb[j];
    __syncthreads();
    float acc = 0.f, accq = 0.f;
    for (int t = 0; t < 64; ++t) {
        float kc = kcol[t];
        acc  += kc * qw[t*64 + j];
        accq += kc * qbs[t];
    }
    KQf[d*64 + j] = acc;
    if (j == 0) kqv[d] = accq;
    if (d == 0) {
        float vb = 0.f;
        for (int t = 0; t < 64; ++t) vb += kbs[t] * qw[t*64 + j];
        bqv[j] = vb;
        if (j == 0) {
            float c0 = 0.f;
            for (int t = 0; t < 64; ++t) c0 += kbs[t] * qbs[t];
            *c0p = c0;
        }
    }
}

// ------ pack_kq: KQP[k4*64+o] = (KQ[4k4+0..3][o]) for dot4 -------------------
__global__ __launch_bounds__(256) void pack_kq(const float* __restrict__ KQf,
                                               float4* __restrict__ KQP)
{
    int i = blockIdx.x * 256 + threadIdx.x;
    if (i < 1024) {
        int o = i & 63, k4 = i >> 6;
        KQP[i] = make_float4(KQf[(4*k4+0)*64 + o], KQf[(4*k4+1)*64 + o],
                             KQf[(4*k4+2)*64 + o], KQf[(4*k4+3)*64 + o]);
    }
}

// -------- G4[v][j] = (sum_k emb[v][k]*w_ih[{0,64,128}+j][k] + b, pad) --------
__global__ __launch_bounds__(64) void build_G(const float* __restrict__ embed_w,
                                              const float* __restrict__ w_ih,
                                              const float* __restrict__ b_ih,
                                              float4* __restrict__ G4)
{
    int v = blockIdx.x, j = threadIdx.x;
    __shared__ float e_s[64];
    e_s[j] = embed_w[v*64 + j];
    __syncthreads();
    float a0 = b_ih[j], a1 = b_ih[64 + j], a2 = b_ih[128 + j];
    for (int k = 0; k < 64; ++k) {
        float e = e_s[k];
        a0 += e * w_ih[j*128 + k];
        a1 += e * w_ih[(64 + j)*128 + k];
        a2 += e * w_ih[(128 + j)*128 + k];
    }
    G4[v*64 + j] = make_float4(a0, a1, a2, 0.f);
}

// ------- k/v precompute: K' (folded) pairs; v m-pair-transposed; c[b][m] -----
__global__ __launch_bounds__(256) void compute_kv(const float* __restrict__ memory,
                                                  const float* __restrict__ bqv,
                                                  const float* __restrict__ val_b,
                                                  const float4* __restrict__ KQP,
                                                  const float4* __restrict__ VWP,
                                                  const float* __restrict__ kqv,
                                                  const float* __restrict__ c0p,
                                                  unsigned* __restrict__ kT2,
                                                  unsigned* __restrict__ vT2,
                                                  float* __restrict__ cB)
{
    int wid = threadIdx.x >> 6;
    int o   = threadIdx.x & 63;
    int row = blockIdx.x * 4 + wid;          // row = b*256 + m
    int b = row >> 8, m = row & 255;
    __shared__ __align__(16) float mem_s[4][64];
    __shared__ float avs[4][64];
    mem_s[wid][o] = memory[(size_t)row * 64 + o];
    __syncthreads();
    float ak = bqv[o], av = val_b[o], ac = *c0p;
    const float4* m4  = (const float4*)mem_s[wid];
    const float4* kq4 = (const float4*)kqv;
#pragma unroll
    for (int k4 = 0; k4 < 16; ++k4) {
        float4 mm = m4[k4];
        ak += dot4(mm, KQP[k4*64 + o]);
        av += dot4(mm, VWP[k4*64 + o]);
        ac += dot4(mm, kq4[k4]);
    }
    float nb = __shfl_xor(ak, 1);            // K'[o^1][m]
    if ((o & 1) == 0)                        // pair (K'[o][m], K'[o+1][m])
        kT2[((size_t)b*32 + (o >> 1))*256 + m] = h2rn(ak, nb);
    avs[wid][o] = av;
    if (o == 0) cB[row] = ac;
    __syncthreads();
    if ((wid & 1) == 0) {                    // pair (v[m][o], v[m+1][o]), m even
        vT2[((size_t)b*64 + o)*128 + (m >> 1)] = h2rn(avs[wid][o], avs[wid+1][o]);
    }
}

// two interleaved GRU steps (independent batch chains, shared weights).
// G values consumed at the tails (late-add); per-b math identical to R24.
#define GRU_STEP2(cA0, cA1, cA2, cB0, cB1, cB2) do {                        \
    float gr0 = RrB0, gz0 = RzB0, gn0 = bhn;                                \
    float gr1 = RrB1, gz1 = RzB1, gn1 = bhn;                                \
    _Pragma("unroll")                                                       \
    for (int kp = 0; kp < 32; ++kp) {                                       \
        h2v ha = bch(rl_u(hpu0, 2*kp));                                     \
        h2v hb = bch(rl_u(hpu1, 2*kp));                                     \
        gr0 = FDOT2(ha, wr2[kp], gr0);                                      \
        gr1 = FDOT2(hb, wr2[kp], gr1);                                      \
        gz0 = FDOT2(ha, wz2[kp], gz0);                                      \
        gz1 = FDOT2(hb, wz2[kp], gz1);                                      \
        gn0 = FDOT2(ha, wn2[kp], gn0);                                      \
        gn1 = FDOT2(hb, wn2[kp], gn1);                                      \
    }                                                                       \
    float r_0 = sigm(gr0 + (cA0));                                          \
    float r_1 = sigm(gr1 + (cB0));                                          \
    float z_0 = sigm(gz0 + (cA1));                                          \
    float z_1 = sigm(gz1 + (cB1));                                          \
    float n_0 = tanh_f(((cA2) + Rn0) + r_0 * gn0);                          \
    float n_1 = tanh_f(((cB2) + Rn1) + r_1 * gn1);                          \
    h0 = fmaf(z_0, h0 - n_0, n_0);                                          \
    h1 = fmaf(z_1, h1 - n_1, n_1);                                          \
    hpu0 = pkrtz(h0, __shfl_xor(h0, 1));                                    \
    hpu1 = pkrtz(h1, __shfl_xor(h1, 1));                                    \
} while (0)

// -------- main recurrent kernel: 1 wave per TWO batch elements ---------------
__global__ __launch_bounds__(64, 1) void recurrent_main(
    const int*   __restrict__ seq,
    const float* __restrict__ b_hh,
    const float* __restrict__ head_w,
    const float* __restrict__ head_b,
    const unsigned* __restrict__ kT2g,
    const unsigned* __restrict__ vT2g,
    const float4* __restrict__ G4,
    const unsigned* __restrict__ WPhh2,
    const unsigned* __restrict__ WR2p,
    const float* __restrict__ cB,
    float* __restrict__ out)
{
    const int b0 = blockIdx.x * 2;
    const int b1 = b0 + 1;
    const int j = threadIdx.x;

    extern __shared__ __align__(16) char smem[];
    const uint4* kT0_lds = (const uint4*)(smem + S_KT0);
    const uint4* kT1_lds = (const uint4*)(smem + S_KT1);

    // ---- stage both K'T2 and both vT2 (repad 128->132 u32 rows) ----
    {
        const uint4* kTg0 = (const uint4*)(kT2g + (size_t)b0 * 8192);
        const uint4* kTg1 = (const uint4*)(kT2g + (size_t)b1 * 8192);
        uint4* kTls0 = (uint4*)(smem + S_KT0);
        uint4* kTls1 = (uint4*)(smem + S_KT1);
#pragma unroll
        for (int i = 0; i < 32; ++i) {
            kTls0[i*64 + j] = kTg0[i*64 + j];
            kTls1[i*64 + j] = kTg1[i*64 + j];
        }
        const uint4* vg0 = (const uint4*)(vT2g + (size_t)b0 * 8192);
        const uint4* vg1 = (const uint4*)(vT2g + (size_t)b1 * 8192);
        uint4* vls0 = (uint4*)(smem + S_V0);
        uint4* vls1 = (uint4*)(smem + S_V1);
#pragma unroll
        for (int i = 0; i < 32; ++i) {
            int t = i*64 + j;                 // global quad: o = t>>5, q = t&31
            vls0[(t >> 5)*33 + (t & 31)] = vg0[t];
            vls1[(t >> 5)*33 + (t & 31)] = vg1[t];
        }
    }

    // ---- shared weight tables in registers (compiler parks in AGPRs) ----
    h2v wr2[32], wz2[32], wn2[32];
#pragma unroll
    for (int k2 = 0; k2 < 32; ++k2) {
        wr2[k2] = bch(WPhh2[(k2*3 + 0)*64 + j]);
        wz2[k2] = bch(WPhh2[(k2*3 + 1)*64 + j]);
        wn2[k2] = bch(WPhh2[(k2*3 + 2)*64 + j]);
    }
    h2v rr2[32], rz2[32], rn2[32];
#pragma unroll
    for (int k2 = 0; k2 < 32; ++k2) {
        rr2[k2] = bch(WR2p[(k2*3 + 0)*64 + j]);
        rz2[k2] = bch(WR2p[(k2*3 + 1)*64 + j]);
        rn2[k2] = bch(WR2p[(k2*3 + 2)*64 + j]);
    }

    float h0 = 0.f, h1 = 0.f;            // lane j owns h[j] of both chains
    unsigned hpu0 = 0u, hpu1 = 0u;       // packed (h[2t], h[2t+1]) fp16 pairs
    const float bhr = b_hh[j], bhz = b_hh[64 + j], bhn = b_hh[128 + j];
    const float4 cc0 = *(const float4*)(cB + (size_t)b0*256 + 4*j);
    const float4 cc1 = *(const float4*)(cB + (size_t)b1*256 + 4*j);

    const int* seqb0 = seq + (size_t)b0 * L_;
    const int* seqb1 = seq + (size_t)b1 * L_;
    const uint4* vrow0 = (const uint4*)(smem + S_V0) + j*33;
    const uint4* vrow1 = (const uint4*)(smem + S_V1) + j*33;
    __builtin_amdgcn_wave_barrier();

    for (int c = 0; c < C_; ++c) {
        const int c16 = c * F_;

        // ---- tokens (both chains): wave-uniform -> SGPRs ----
        const int4 qA = *(const int4*)(seqb0 + c16);
        const int4 qB = *(const int4*)(seqb0 + c16 + 4);
        const int4 qC = *(const int4*)(seqb0 + c16 + 8);
        const int4 qD = *(const int4*)(seqb0 + c16 + 12);
        const int4 wA = *(const int4*)(seqb1 + c16);
        const int4 wB = *(const int4*)(seqb1 + c16 + 4);
        const int4 wC = *(const int4*)(seqb1 + c16 + 8);
        const int4 wD = *(const int4*)(seqb1 + c16 + 12);
        const int tA0 = __builtin_amdgcn_readfirstlane(qA.x);
        const int tA1 = __builtin_amdgcn_readfirstlane(qA.y);
        const int tA2 = __builtin_amdgcn_readfirstlane(qA.z);
        const int tA3 = __builtin_amdgcn_readfirstlane(qA.w);
        const int tB0 = __builtin_amdgcn_readfirstlane(qB.x);
        const int tB1 = __builtin_amdgcn_readfirstlane(qB.y);
        const int tB2 = __builtin_amdgcn_readfirstlane(qB.z);
        const int tB3 = __builtin_amdgcn_readfirstlane(qB.w);
        const int tC0 = __builtin_amdgcn_readfirstlane(qC.x);
        const int tC1 = __builtin_amdgcn_readfirstlane(qC.y);
        const int tC2 = __builtin_amdgcn_readfirstlane(qC.z);
        const int tC3 = __builtin_amdgcn_readfirstlane(qC.w);
        const int tD0 = __builtin_amdgcn_readfirstlane(qD.x);
        const int tD1 = __builtin_amdgcn_readfirstlane(qD.y);
        const int tD2 = __builtin_amdgcn_readfirstlane(qD.z);
        const int tD3 = __builtin_amdgcn_readfirstlane(qD.w);
        const int uA0 = __builtin_amdgcn_readfirstlane(wA.x);
        const int uA1 = __builtin_amdgcn_readfirstlane(wA.y);
        const int uA2 = __builtin_amdgcn_readfirstlane(wA.z);
        const int uA3 = __builtin_amdgcn_readfirstlane(wA.w);
        const int uB0 = __builtin_amdgcn_readfirstlane(wB.x);
        const int uB1 = __builtin_amdgcn_readfirstlane(wB.y);
        const int uB2 = __builtin_amdgcn_readfirstlane(wB.z);
        const int uB3 = __builtin_amdgcn_readfirstlane(wB.w);
        const int uC0 = __builtin_amdgcn_readfirstlane(wC.x);
        const int uC1 = __builtin_amdgcn_readfirstlane(wC.y);
        const int uC2 = __builtin_amdgcn_readfirstlane(wC.z);
        const int uC3 = __builtin_amdgcn_readfirstlane(wC.w);
        const int uD0 = __builtin_amdgcn_readfirstlane(wD.x);
        const int uD1 = __builtin_amdgcn_readfirstlane(wD.y);
        const int uD2 = __builtin_amdgcn_readfirstlane(wD.z);
        const int uD3 = __builtin_amdgcn_readfirstlane(wD.w);

        // ---- scores, both chains interleaved: lane j owns m = 4j..4j+3 ----
        float s00 = cc0.x, s01 = cc0.y, s02 = cc0.z, s03 = cc0.w;
        float s10 = cc1.x, s11 = cc1.y, s12 = cc1.z, s13 = cc1.w;
#pragma unroll 8
        for (int t = 0; t < 32; ++t) {
            h2v qq0 = bch(rl_u(hpu0, 2*t));
            h2v qq1 = bch(rl_u(hpu1, 2*t));
            uint4 k0 = kT0_lds[t*64 + j];
            uint4 k1 = kT1_lds[t*64 + j];
            s00 = FDOT2(bch(k0.x), qq0, s00);
            s10 = FDOT2(bch(k1.x), qq1, s10);
            s01 = FDOT2(bch(k0.y), qq0, s01);
            s11 = FDOT2(bch(k1.y), qq1, s11);
            s02 = FDOT2(bch(k0.z), qq0, s02);
            s12 = FDOT2(bch(k1.z), qq1, s12);
            s03 = FDOT2(bch(k0.w), qq0, s03);
            s13 = FDOT2(bch(k1.w), qq1, s13);
        }
        const float scale = 0.125f;
        float4 p0, p1;
        p0.x = __expf(s00*scale); p0.y = __expf(s01*scale);
        p0.z = __expf(s02*scale); p0.w = __expf(s03*scale);
        p1.x = __expf(s10*scale); p1.y = __expf(s11*scale);
        p1.z = __expf(s12*scale); p1.w = __expf(s13*scale);
        const unsigned pp00 = pkrtz(p0.x, p0.y);
        const unsigned pp01 = pkrtz(p0.z, p0.w);
        const unsigned pp10 = pkrtz(p1.x, p1.y);
        const unsigned pp11 = pkrtz(p1.z, p1.w);
        float sum0 = (p0.x + p0.y) + (p0.z + p0.w);
        float sum1 = (p1.x + p1.y) + (p1.z + p1.w);
#pragma unroll
        for (int o = 32; o > 0; o >>= 1) {
            sum0 += __shfl_xor(sum0, o);
            sum1 += __shfl_xor(sum1, o);
        }
        float inv0 = fast_rcp(sum0);
        float inv1 = fast_rcp(sum1);

        // ---- retrieved, both chains: lane j owns ret[j]; p via readlane ----
        float r00 = 0.f, r01 = 0.f, r02 = 0.f, r03 = 0.f;
        float r10 = 0.f, r11 = 0.f, r12 = 0.f, r13 = 0.f;
#pragma unroll 8
        for (int qd = 0; qd < 32; ++qd) {
            uint4 v0 = vrow0[qd];
            uint4 v1 = vrow1[qd];
            unsigned px0 = rl_u(pp00, 2*qd);
            unsigned px1 = rl_u(pp10, 2*qd);
            unsigned py0 = rl_u(pp01, 2*qd);
            unsigned py1 = rl_u(pp11, 2*qd);
            unsigned pz0 = rl_u(pp00, 2*qd + 1);
            unsigned pz1 = rl_u(pp10, 2*qd + 1);
            unsigned pw0 = rl_u(pp01, 2*qd + 1);
            unsigned pw1 = rl_u(pp11, 2*qd + 1);
            r00 = FDOT2(bch(px0), bch(v0.x), r00);
            r10 = FDOT2(bch(px1), bch(v1.x), r10);
            r01 = FDOT2(bch(py0), bch(v0.y), r01);
            r11 = FDOT2(bch(py1), bch(v1.y), r11);
            r02 = FDOT2(bch(pz0), bch(v0.z), r02);
            r12 = FDOT2(bch(pz1), bch(v1.z), r12);
            r03 = FDOT2(bch(pw0), bch(v0.w), r03);
            r13 = FDOT2(bch(pw1), bch(v1.w), r13);
        }
        float ret0 = ((r00 + r01) + (r02 + r03)) * inv0;
        float ret1 = ((r10 + r11) + (r12 + r13)) * inv1;

        // ---- R matvec, both chains: WR shared in regs ----
        unsigned rpu0 = pkrtz(ret0, __shfl_xor(ret0, 1));
        unsigned rpu1 = pkrtz(ret1, __shfl_xor(ret1, 1));
        float Rr0 = 0.f, Rz0 = 0.f, Rn0 = 0.f;
        float Rr1 = 0.f, Rz1 = 0.f, Rn1 = 0.f;
#pragma unroll
        for (int k2 = 0; k2 < 32; ++k2) {
            h2v ra = bch(rl_u(rpu0, 2*k2));
            h2v rb = bch(rl_u(rpu1, 2*k2));
            Rr0 = FDOT2(ra, rr2[k2], Rr0);
            Rr1 = FDOT2(rb, rr2[k2], Rr1);
            Rz0 = FDOT2(ra, rz2[k2], Rz0);
            Rz1 = FDOT2(rb, rz2[k2], Rz1);
            Rn0 = FDOT2(ra, rn2[k2], Rn0);
            Rn1 = FDOT2(rb, rn2[k2], Rn1);
        }
        const float RrB0 = Rr0 + bhr, RzB0 = Rz0 + bhz;
        const float RrB1 = Rr1 + bhr, RzB1 = Rz1 + bhz;

        // ---- 16 GRU steps x 2 chains: 4 groups x 4 interleaved steps ----
#pragma unroll 1
        for (int g = 0; g < 4; ++g) {
            const bool gb1 = (g & 1), gb2 = (g & 2);
            const int x0 = gb2 ? (gb1 ? tD0 : tC0) : (gb1 ? tB0 : tA0);
            const int x1 = gb2 ? (gb1 ? tD1 : tC1) : (gb1 ? tB1 : tA1);
            const int x2 = gb2 ? (gb1 ? tD2 : tC2) : (gb1 ? tB2 : tA2);
            const int x3 = gb2 ? (gb1 ? tD3 : tC3) : (gb1 ? tB3 : tA3);
            const int y0 = gb2 ? (gb1 ? uD0 : uC0) : (gb1 ? uB0 : uA0);
            const int y1 = gb2 ? (gb1 ? uD1 : uC1) : (gb1 ? uB1 : uA1);
            const int y2 = gb2 ? (gb1 ? uD2 : uC2) : (gb1 ? uB2 : uA2);
            const int y3 = gb2 ? (gb1 ? uD3 : uC3) : (gb1 ? uB3 : uA3);
            const float4 fA0 = G4[x0*64 + j], fA1 = G4[y0*64 + j];
            const float4 fB0 = G4[x1*64 + j], fB1 = G4[y1*64 + j];
            const float4 fC0 = G4[x2*64 + j], fC1 = G4[y2*64 + j];
            const float4 fD0 = G4[x3*64 + j], fD1 = G4[y3*64 + j];

            GRU_STEP2(fA0.x, fA0.y, fA0.z, fA1.x, fA1.y, fA1.z);
            GRU_STEP2(fB0.x, fB0.y, fB0.z, fB1.x, fB1.y, fB1.z);
            GRU_STEP2(fC0.x, fC0.y, fC0.z, fC1.x, fC1.y, fC1.z);
            GRU_STEP2(fD0.x, fD0.y, fD0.z, fD1.x, fD1.y, fD1.z);
        }
    }

    // ---- head: both chains (fp32) ----
    float o0 = head_b[j], o1 = o0;
#pragma unroll
    for (int k4 = 0; k4 < 16; ++k4) {
        const float* hw = head_w + j*64 + 4*k4;
        float a0 = rl(h0, 4*k4+0), a1 = rl(h0, 4*k4+1);
        float a2 = rl(h0, 4*k4+2), a3 = rl(h0, 4*k4+3);
        float b0v = rl(h1, 4*k4+0), b1v = rl(h1, 4*k4+1);
        float b2v = rl(h1, 4*k4+2), b3v = rl(h1, 4*k4+3);
        o0 += a0*hw[0] + a1*hw[1] + a2*hw[2] + a3*hw[3];
        o1 += b0v*hw[0] + b1v*hw[1] + b2v*hw[2] + b3v*hw[3];
    }
    out[(size_t)b0*64 + j] = o0;
    out[(size_t)b1*64 + j] = o1;
}

extern "C" void kernel_launch(void* const* d_in, const int* in_sizes, int n_in,
                              void* d_out, int out_size, void* d_ws, size_t ws_size,
                              hipStream_t stream) {
    const int*   seq      = (const int*)  d_in[0];
    const float* memory   = (const float*)d_in[1];
    const float* embed_w  = (const float*)d_in[2];
    const float* w_ih     = (const float*)d_in[3];
    const float* w_hh     = (const float*)d_in[4];
    const float* b_ih     = (const float*)d_in[5];
    const float* b_hh     = (const float*)d_in[6];
    const float* key_w    = (const float*)d_in[7];
    const float* key_b    = (const float*)d_in[8];
    const float* val_w    = (const float*)d_in[9];
    const float* val_b    = (const float*)d_in[10];
    const float* query_w  = (const float*)d_in[11];
    const float* query_b  = (const float*)d_in[12];
    const float* head_w   = (const float*)d_in[13];
    const float* head_b   = (const float*)d_in[14];

    char* ws = (char*)d_ws;
    unsigned* kT2  = (unsigned*)(ws + WS_KT);
    unsigned* vT2  = (unsigned*)(ws + WS_V);
    float4*   G4   = (float4*)  (ws + WS_G4);
    unsigned* WPhh2 = (unsigned*)(ws + WS_WPHH);
    unsigned* WR2p  = (unsigned*)(ws + WS_WR);
    float4*   KQP   = (float4*)  (ws + WS_KQP);
    float4*   VWP   = (float4*)  (ws + WS_VWP);
    float*    KQf   = (float*)   (ws + WS_KQF);
    float*    bqv   = (float*)   (ws + WS_BQ);
    float*    kqv   = (float*)   (ws + WS_KQV);
    float*    c0p   = (float*)   (ws + WS_C0);
    float*    cB    = (float*)   (ws + WS_CB);

    (void)hipFuncSetAttribute((const void*)recurrent_main,
                              hipFuncAttributeMaxDynamicSharedMemorySize,
                              (int)SMEM_BYTES);

    pack_weights<<<64, 256, 0, stream>>>(w_ih, w_hh, val_w, WPhh2, WR2p, VWP);
    fold_kq<<<64, 64, 0, stream>>>(key_w, query_w, key_b, query_b,
                                   KQf, bqv, kqv, c0p);
    pack_kq<<<4, 256, 0, stream>>>(KQf, KQP);
    build_G<<<64, 64, 0, stream>>>(embed_w, w_ih, b_ih, G4);
    compute_kv<<<(B_*M_)/4, 256, 0, stream>>>(memory, bqv, val_b, KQP, VWP,
                                              kqv, c0p, kT2, vT2, cB);
    recurrent_main<<<B_/2, 64, SMEM_BYTES, stream>>>(seq, b_hh, head_w, head_b,
                                                     kT2, vT2, G4, WPhh2, WR2p, cB,
                                                     (float*)d_out);
}

// Round 14
// 1263.886 us; speedup vs baseline: 1.6831x; 1.6831x over previous
//
#include <hip/hip_runtime.h>
#include <hip/hip_fp16.h>

// FixedFreqModel: B=512, L=2048, M=256, H=64, VOCAB=64, READ_FREQ=16.
// R26 = R24 verbatim (best measured: 1050us steady / ~1271us harness).
// R25 (2-chain ILP merge) regressed 1.8x: at 2 waves/CU the waves run on
// DIFFERENT SIMDs concurrently; merging serialized them onto one SIMD
// (VALUBusy 35.4->19.2 with identical busy-cycles). Reverted.
// R24 = R23 + G4 float4 repack + SGPR token scalarization.
// Kernel history: KQ-fold (q-matvec eliminated), p-via-readlane (no LDS
// round-trip), v-loop 4-acc, late-add G, 4-group GRU + s_cselect tokens,
// W_hh + WR register-resident, no pins.

#define B_ 512
#define L_ 2048
#define M_ 256
#define H_ 64
#define C_ 128
#define F_ 16

typedef float v2f __attribute__((ext_vector_type(2)));
typedef _Float16 h2v __attribute__((ext_vector_type(2)));

#if __has_builtin(__builtin_amdgcn_fdot2)
__device__ __forceinline__ float FDOT2(h2v a, h2v b, float c) {
    return __builtin_amdgcn_fdot2(a, b, c, false);
}
#else
__device__ __forceinline__ float FDOT2(h2v a, h2v b, float c) {
    return c + (float)a[0]*(float)b[0] + (float)a[1]*(float)b[1];
}
#endif

__device__ __forceinline__ h2v bch(unsigned u) { return __builtin_bit_cast(h2v, u); }
__device__ __forceinline__ unsigned rl_u(unsigned v, int lane) {
    return (unsigned)__builtin_amdgcn_readlane((int)v, lane);
}
__device__ __forceinline__ float rl(float v, int lane) {
    return __int_as_float(__builtin_amdgcn_readlane(__float_as_int(v), lane));
}
__device__ __forceinline__ unsigned pkrtz(float a, float b) {
    auto r = __builtin_amdgcn_cvt_pkrtz(a, b);     // __fp16 ext_vector(2)
    return __builtin_bit_cast(unsigned, r);
}
__device__ __forceinline__ float dot4(float4 a, float4 b) {
    return a.x*b.x + a.y*b.y + a.z*b.z + a.w*b.w;
}
__device__ __forceinline__ float fast_rcp(float x) { return __builtin_amdgcn_rcpf(x); }
__device__ __forceinline__ float sigm(float x) { return fast_rcp(1.f + __expf(-x)); }
__device__ __forceinline__ float tanh_f(float x) {
    float e2 = __expf(-2.f * fabsf(x));
    return copysignf((1.f - e2) * fast_rcp(1.f + e2), x);
}
__device__ __forceinline__ unsigned h2rn(float a, float b) {
    __half2 h = __floats2half2_rn(a, b);
    return __builtin_bit_cast(unsigned, h);
}

// workspace offsets (bytes)
#define WS_KT    0u            // K'T2: 512 * 8192 u32 = 16 MB  [b][hh2][m]
#define WS_V     16777216u     // vT2: 512 * 8192 u32 = 16 MB  [b][o][mp]
#define WS_G4    33554432u     // 64*64 float4 = 64 KB  (a0,a1,a2,pad)
#define WS_WPHH  33619968u     // 6144 u32 = 24 KB  [(k2*3+g)*64+j]
#define WS_WR    33644544u     // 6144 u32 = 24 KB
#define WS_KQP   33669120u     // 1024 float4 = 16 KB (folded K.Q, packed)
#define WS_VWP   33685504u     // 16 KB
#define WS_KQF   33701888u     // 4096 fp32 = 16 KB (KQ scalar, pre-pack)
#define WS_BQ    33718272u     // 64 fp32 (bq = kb.Wq)
#define WS_KQV   33718528u     // 64 fp32 (kq = Kw^T qb)
#define WS_C0    33718784u     // 1 fp32 (c0 = kb.qb), padded
#define WS_CB    33719040u     // 512*256 fp32 = 512 KB (c[b][m])

// dynamic LDS layout (bytes)
#define S_KT   0u        // 32768 : K'T2 u32 [hh2=32][m=256]
#define S_V    32768u    // 33792 : vP u32 [o=64][132] (128 mp-pairs + 4 pad)
#define SMEM_BYTES 66560u

// ---------------- pack weights -----------------------------------------------
__global__ void pack_weights(const float* __restrict__ w_ih,
                             const float* __restrict__ w_hh,
                             const float* __restrict__ vw,
                             unsigned* __restrict__ WPhh2,
                             unsigned* __restrict__ WR2p,
                             float4* __restrict__ VWP)
{
    int idx = blockIdx.x * 256 + threadIdx.x;
    if (idx < 6144) {                        // WPhh2[(k2*3+g)*64+j]
        int j = idx & 63, t = idx >> 6, g = t % 3, k2 = t / 3;
        const float* s = w_hh + (g*64 + j)*64 + 2*k2;
        WPhh2[idx] = h2rn(s[0], s[1]);
    } else if (idx < 12288) {                // WR2p: retrieved half of w_ih
        int i = idx - 6144;
        int j = i & 63, t = i >> 6, g = t % 3, k2 = t / 3;
        const float* s = w_ih + (g*64 + j)*128 + 64 + 2*k2;
        WR2p[i] = h2rn(s[0], s[1]);
    } else if (idx < 13312) {                // VWP
        int i = idx - 12288;
        int j = i & 63, k4 = i >> 6;
        const float* s = vw + j*64 + 4*k4;
        VWP[i] = make_float4(s[0], s[1], s[2], s[3]);
    }
}

// ------ fold_kq: KQ[d][j] = sum_t Kw[t][d]*Wq[t][j]; bq, kq, c0 --------------
__global__ __launch_bounds__(64) void fold_kq(const float* __restrict__ kw,
                                              const float* __restrict__ qw,
                                              const float* __restrict__ kb,
                                              const float* __restrict__ qb,
                                              float* __restrict__ KQf,
                                              float* __restrict__ bqv,
                                              float* __restrict__ kqv,
                                              float* __restrict__ c0p)
{
    int d = blockIdx.x, j = threadIdx.x;
    __shared__ float kcol[64], kbs[64], qbs[64];
    kcol[j] = kw[j*64 + d];
    kbs[j]  = kb[j];
    qbs[j]  = qb[j];
    __syncthreads();
    float acc = 0.f, accq = 0.f;
    for (int t = 0; t < 64; ++t) {
        float kc = kcol[t];
        acc  += kc * qw[t*64 + j];
        accq += kc * qbs[t];
    }
    KQf[d*64 + j] = acc;
    if (j == 0) kqv[d] = accq;
    if (d == 0) {
        float vb = 0.f;
        for (int t = 0; t < 64; ++t) vb += kbs[t] * qw[t*64 + j];
        bqv[j] = vb;
        if (j == 0) {
            float c0 = 0.f;
            for (int t = 0; t < 64; ++t) c0 += kbs[t] * qbs[t];
            *c0p = c0;
        }
    }
}

// ------ pack_kq: KQP[k4*64+o] = (KQ[4k4+0..3][o]) for dot4 -------------------
__global__ __launch_bounds__(256) void pack_kq(const float* __restrict__ KQf,
                                               float4* __restrict__ KQP)
{
    int i = blockIdx.x * 256 + threadIdx.x;
    if (i < 1024) {
        int o = i & 63, k4 = i >> 6;
        KQP[i] = make_float4(KQf[(4*k4+0)*64 + o], KQf[(4*k4+1)*64 + o],
                             KQf[(4*k4+2)*64 + o], KQf[(4*k4+3)*64 + o]);
    }
}

// -------- G4[v][j] = (sum_k emb[v][k]*w_ih[{0,64,128}+j][k] + b, pad) --------
__global__ __launch_bounds__(64) void build_G(const float* __restrict__ embed_w,
                                              const float* __restrict__ w_ih,
                                              const float* __restrict__ b_ih,
                                              float4* __restrict__ G4)
{
    int v = blockIdx.x, j = threadIdx.x;
    __shared__ float e_s[64];
    e_s[j] = embed_w[v*64 + j];
    __syncthreads();
    float a0 = b_ih[j], a1 = b_ih[64 + j], a2 = b_ih[128 + j];
    for (int k = 0; k < 64; ++k) {
        float e = e_s[k];
        a0 += e * w_ih[j*128 + k];
        a1 += e * w_ih[(64 + j)*128 + k];
        a2 += e * w_ih[(128 + j)*128 + k];
    }
    G4[v*64 + j] = make_float4(a0, a1, a2, 0.f);
}

// ------- k/v precompute: K' (folded) pairs; v m-pair-transposed; c[b][m] -----
__global__ __launch_bounds__(256) void compute_kv(const float* __restrict__ memory,
                                                  const float* __restrict__ bqv,
                                                  const float* __restrict__ val_b,
                                                  const float4* __restrict__ KQP,
                                                  const float4* __restrict__ VWP,
                                                  const float* __restrict__ kqv,
                                                  const float* __restrict__ c0p,
                                                  unsigned* __restrict__ kT2,
                                                  unsigned* __restrict__ vT2,
                                                  float* __restrict__ cB)
{
    int wid = threadIdx.x >> 6;
    int o   = threadIdx.x & 63;
    int row = blockIdx.x * 4 + wid;          // row = b*256 + m
    int b = row >> 8, m = row & 255;
    __shared__ __align__(16) float mem_s[4][64];
    __shared__ float avs[4][64];
    mem_s[wid][o] = memory[(size_t)row * 64 + o];
    __syncthreads();
    float ak = bqv[o], av = val_b[o], ac = *c0p;
    const float4* m4  = (const float4*)mem_s[wid];
    const float4* kq4 = (const float4*)kqv;
#pragma unroll
    for (int k4 = 0; k4 < 16; ++k4) {
        float4 mm = m4[k4];
        ak += dot4(mm, KQP[k4*64 + o]);
        av += dot4(mm, VWP[k4*64 + o]);
        ac += dot4(mm, kq4[k4]);
    }
    float nb = __shfl_xor(ak, 1);            // K'[o^1][m]
    if ((o & 1) == 0)                        // pair (K'[o][m], K'[o+1][m])
        kT2[((size_t)b*32 + (o >> 1))*256 + m] = h2rn(ak, nb);
    avs[wid][o] = av;
    if (o == 0) cB[row] = ac;
    __syncthreads();
    if ((wid & 1) == 0) {                    // pair (v[m][o], v[m+1][o]), m even
        vT2[((size_t)b*64 + o)*128 + (m >> 1)] = h2rn(avs[wid][o], avs[wid+1][o]);
    }
}

// one GRU step: h broadcast as half2 via readlane; dot2 matvec; no LDS.
// G values (cg0/cg1) consumed at the TAIL so their load latency hides
// under the ~256cy matvec (fp32 reassociation only).
#define GRU_STEP(cg0, cg1, cg2) do {                                        \
    float gr = RrB, gz = RzB, gn = bhn;                                     \
    _Pragma("unroll")                                                       \
    for (int kp = 0; kp < 32; ++kp) {                                       \
        h2v hhp = bch(rl_u(hpu, 2*kp));                                     \
        gr = FDOT2(hhp, wr2[kp], gr);                                       \
        gz = FDOT2(hhp, wz2[kp], gz);                                       \
        gn = FDOT2(hhp, wn2[kp], gn);                                       \
    }                                                                       \
    float r_ = sigm(gr + (cg0));                                            \
    float z_ = sigm(gz + (cg1));                                            \
    float n_ = tanh_f(((cg2) + Rn) + r_ * gn);                              \
    h = fmaf(z_, h - n_, n_);                                               \
    float hx_ = __shfl_xor(h, 1);                                           \
    hpu = pkrtz(h, hx_);                                                    \
} while (0)

// ---------------- main recurrent kernel: 1 wave per batch element ------------
__global__ __launch_bounds__(64, 1) void recurrent_main(
    const int*   __restrict__ seq,
    const float* __restrict__ b_hh,
    const float* __restrict__ head_w,
    const float* __restrict__ head_b,
    const unsigned* __restrict__ kT2g,
    const unsigned* __restrict__ vT2g,
    const float4* __restrict__ G4,
    const unsigned* __restrict__ WPhh2,
    const unsigned* __restrict__ WR2p,
    const float* __restrict__ cB,
    float* __restrict__ out)
{
    const int b = blockIdx.x;
    const int j = threadIdx.x;

    extern __shared__ __align__(16) char smem[];
    const uint4* kT2_lds = (const uint4*)(smem + S_KT);  // [hh2*64 + j]: 4 m-pairs

    // ---- stage K'T2, vT2 (repad 128->132 u32 rows) into LDS once ----
    {
        const uint4* kTg = (const uint4*)(kT2g + (size_t)b * 8192);
        uint4* kTls = (uint4*)(smem + S_KT);
#pragma unroll
        for (int i = 0; i < 32; ++i) kTls[i*64 + j] = kTg[i*64 + j];
        const uint4* vg4 = (const uint4*)(vT2g + (size_t)b * 8192);
        uint4* vls4 = (uint4*)(smem + S_V);
#pragma unroll
        for (int i = 0; i < 32; ++i) {
            int t = i*64 + j;                 // global quad: o = t>>5, q = t&31
            vls4[(t >> 5)*33 + (t & 31)] = vg4[t];
        }
    }

    // ---- W_hh in registers as half2: 96 words (compiler parks in AGPRs) ----
    h2v wr2[32], wz2[32], wn2[32];
#pragma unroll
    for (int k2 = 0; k2 < 32; ++k2) {
        wr2[k2] = bch(WPhh2[(k2*3 + 0)*64 + j]);
        wz2[k2] = bch(WPhh2[(k2*3 + 1)*64 + j]);
        wn2[k2] = bch(WPhh2[(k2*3 + 2)*64 + j]);
    }
    // ---- WR (retrieved-half of w_ih) likewise: 96 words, loaded ONCE ----
    h2v rr2[32], rz2[32], rn2[32];
#pragma unroll
    for (int k2 = 0; k2 < 32; ++k2) {
        rr2[k2] = bch(WR2p[(k2*3 + 0)*64 + j]);
        rz2[k2] = bch(WR2p[(k2*3 + 1)*64 + j]);
        rn2[k2] = bch(WR2p[(k2*3 + 2)*64 + j]);
    }

    float h = 0.f;                       // lane j owns h[j]; never leaves regs
    unsigned hpu = 0u;                   // packed (h[2t], h[2t+1]) fp16 pair
    const float bhr = b_hh[j], bhz = b_hh[64 + j], bhn = b_hh[128 + j];
    // scores bias: c[b][m] for lane's m = 4j..4j+3 (fp32, in regs all session)
    const float4 cc = *(const float4*)(cB + (size_t)b*256 + 4*j);

    const int* seqb = seq + (size_t)b * L_;
    const uint4* vrow = (const uint4*)(smem + S_V) + j*33;   // lane's o-row
    __builtin_amdgcn_wave_barrier();

    for (int c = 0; c < C_; ++c) {
        const int c16 = c * F_;

        // ---- tokens: wave-uniform -> force into SGPRs (selects become
        //      s_cselect, G addresses become saddr+voffset) ----
        const int4 qA = *(const int4*)(seqb + c16);
        const int4 qB = *(const int4*)(seqb + c16 + 4);
        const int4 qC = *(const int4*)(seqb + c16 + 8);
        const int4 qD = *(const int4*)(seqb + c16 + 12);
        const int tA0 = __builtin_amdgcn_readfirstlane(qA.x);
        const int tA1 = __builtin_amdgcn_readfirstlane(qA.y);
        const int tA2 = __builtin_amdgcn_readfirstlane(qA.z);
        const int tA3 = __builtin_amdgcn_readfirstlane(qA.w);
        const int tB0 = __builtin_amdgcn_readfirstlane(qB.x);
        const int tB1 = __builtin_amdgcn_readfirstlane(qB.y);
        const int tB2 = __builtin_amdgcn_readfirstlane(qB.z);
        const int tB3 = __builtin_amdgcn_readfirstlane(qB.w);
        const int tC0 = __builtin_amdgcn_readfirstlane(qC.x);
        const int tC1 = __builtin_amdgcn_readfirstlane(qC.y);
        const int tC2 = __builtin_amdgcn_readfirstlane(qC.z);
        const int tC3 = __builtin_amdgcn_readfirstlane(qC.w);
        const int tD0 = __builtin_amdgcn_readfirstlane(qD.x);
        const int tD1 = __builtin_amdgcn_readfirstlane(qD.y);
        const int tD2 = __builtin_amdgcn_readfirstlane(qD.z);
        const int tD3 = __builtin_amdgcn_readfirstlane(qD.w);

        // ---- scores directly from h pairs (q folded into K'): lane j owns
        //      m = 4j..4j+3; s init = c[m] ----
        float s0 = cc.x, s1 = cc.y, s2 = cc.z, s3 = cc.w;
#pragma unroll 8
        for (int t = 0; t < 32; ++t) {
            h2v qq = bch(rl_u(hpu, 2*t));
            uint4 kk = kT2_lds[t*64 + j];
            s0 = FDOT2(bch(kk.x), qq, s0);
            s1 = FDOT2(bch(kk.y), qq, s1);
            s2 = FDOT2(bch(kk.z), qq, s2);
            s3 = FDOT2(bch(kk.w), qq, s3);
        }
        const float scale = 0.125f;
        // softmax, no max-sub (|s| small), rcp not div
        float4 p;
        p.x = __expf(s0*scale); p.y = __expf(s1*scale);
        p.z = __expf(s2*scale); p.w = __expf(s3*scale);
        // p stays in registers as packed fp16 pairs; v-loop fetches via
        // readlane (no LDS round-trip). ppu0 = pair mp=2j, ppu1 = mp=2j+1.
        const unsigned ppu0 = pkrtz(p.x, p.y);
        const unsigned ppu1 = pkrtz(p.z, p.w);
        float sum = (p.x + p.y) + (p.z + p.w);
#pragma unroll
        for (int o = 32; o > 0; o >>= 1) sum += __shfl_xor(sum, o);
        float inv = fast_rcp(sum);    // consumed only after the v-loop:
                                      // the reduce overlaps the dot2 stream

        // ---- retrieved: lane j owns ret[j]; 4 accs; p via readlane ----
        float r0 = 0.f, r1 = 0.f, r2 = 0.f, r3 = 0.f;
#pragma unroll 8
        for (int qd = 0; qd < 32; ++qd) {
            uint4 vv = vrow[qd];          // pairs mp = 4qd..4qd+3 for o=j
            unsigned px = rl_u(ppu0, 2*qd);      // pair mp=4qd
            unsigned py = rl_u(ppu1, 2*qd);      // pair mp=4qd+1
            unsigned pz = rl_u(ppu0, 2*qd + 1);  // pair mp=4qd+2
            unsigned pw = rl_u(ppu1, 2*qd + 1);  // pair mp=4qd+3
            r0 = FDOT2(bch(px), bch(vv.x), r0);
            r1 = FDOT2(bch(py), bch(vv.y), r1);
            r2 = FDOT2(bch(pz), bch(vv.z), r2);
            r3 = FDOT2(bch(pw), bch(vv.w), r3);
        }
        float ret = ((r0 + r1) + (r2 + r3)) * inv;

        // ---- R matvec: ret packed like h (pairs via shfl); WR in regs ----
        float rx = __shfl_xor(ret, 1);
        unsigned rpu = pkrtz(ret, rx);
        float Rr = 0.f, Rz = 0.f, Rn = 0.f;
#pragma unroll
        for (int k2 = 0; k2 < 32; ++k2) {
            h2v rr = bch(rl_u(rpu, 2*k2));
            Rr = FDOT2(rr, rr2[k2], Rr);
            Rz = FDOT2(rr, rz2[k2], Rz);
            Rn = FDOT2(rr, rn2[k2], Rn);
        }
        const float RrB = Rr + bhr, RzB = Rz + bhz;

        // ---- 16 GRU steps: 4 dynamic groups x 4 unrolled (I-cache OK).
        //      Token select on SGPRs (s_cselect); G4 dwordx4 loads issued
        //      at group top, consumed at step tails (late-add). ----
#pragma unroll 1
        for (int g = 0; g < 4; ++g) {
            const bool gb1 = (g & 1), gb2 = (g & 2);
            const int t0 = gb2 ? (gb1 ? tD0 : tC0) : (gb1 ? tB0 : tA0);
            const int t1 = gb2 ? (gb1 ? tD1 : tC1) : (gb1 ? tB1 : tA1);
            const int t2 = gb2 ? (gb1 ? tD2 : tC2) : (gb1 ? tB2 : tA2);
            const int t3 = gb2 ? (gb1 ? tD3 : tC3) : (gb1 ? tB3 : tA3);
            const float4 gA = G4[t0*64 + j];
            const float4 gB = G4[t1*64 + j];
            const float4 gC = G4[t2*64 + j];
            const float4 gD = G4[t3*64 + j];

            GRU_STEP(gA.x, gA.y, gA.z);
            GRU_STEP(gB.x, gB.y, gB.z);
            GRU_STEP(gC.x, gC.y, gC.z);
            GRU_STEP(gD.x, gD.y, gD.z);
        }
    }

    // ---- head: out[b][j] = head_b[j] + sum_k h[k]*head_w[j][k] (fp32) ----
    float o = head_b[j];
#pragma unroll
    for (int k4 = 0; k4 < 16; ++k4) {
        float h0 = rl(h, 4*k4+0), h1 = rl(h, 4*k4+1);
        float h2 = rl(h, 4*k4+2), h3 = rl(h, 4*k4+3);
        const float* hw = head_w + j*64 + 4*k4;
        o += h0*hw[0] + h1*hw[1] + h2*hw[2] + h3*hw[3];
    }
    out[(size_t)b*64 + j] = o;
}

extern "C" void kernel_launch(void* const* d_in, const int* in_sizes, int n_in,
                              void* d_out, int out_size, void* d_ws, size_t ws_size,
                              hipStream_t stream) {
    const int*   seq      = (const int*)  d_in[0];
    const float* memory   = (const float*)d_in[1];
    const float* embed_w  = (const float*)d_in[2];
    const float* w_ih     = (const float*)d_in[3];
    const float* w_hh     = (const float*)d_in[4];
    const float* b_ih     = (const float*)d_in[5];
    const float* b_hh     = (const float*)d_in[6];
    const float* key_w    = (const float*)d_in[7];
    const float* key_b    = (const float*)d_in[8];
    const float* val_w    = (const float*)d_in[9];
    const float* val_b    = (const float*)d_in[10];
    const float* query_w  = (const float*)d_in[11];
    const float* query_b  = (const float*)d_in[12];
    const float* head_w   = (const float*)d_in[13];
    const float* head_b   = (const float*)d_in[14];

    char* ws = (char*)d_ws;
    unsigned* kT2  = (unsigned*)(ws + WS_KT);
    unsigned* vT2  = (unsigned*)(ws + WS_V);
    float4*   G4   = (float4*)  (ws + WS_G4);
    unsigned* WPhh2 = (unsigned*)(ws + WS_WPHH);
    unsigned* WR2p  = (unsigned*)(ws + WS_WR);
    float4*   KQP   = (float4*)  (ws + WS_KQP);
    float4*   VWP   = (float4*)  (ws + WS_VWP);
    float*    KQf   = (float*)   (ws + WS_KQF);
    float*    bqv   = (float*)   (ws + WS_BQ);
    float*    kqv   = (float*)   (ws + WS_KQV);
    float*    c0p   = (float*)   (ws + WS_C0);
    float*    cB    = (float*)   (ws + WS_CB);

    (void)hipFuncSetAttribute((const void*)recurrent_main,
                              hipFuncAttributeMaxDynamicSharedMemorySize,
                              (int)SMEM_BYTES);

    pack_weights<<<64, 256, 0, stream>>>(w_ih, w_hh, val_w, WPhh2, WR2p, VWP);
    fold_kq<<<64, 64, 0, stream>>>(key_w, query_w, key_b, query_b,
                                   KQf, bqv, kqv, c0p);
    pack_kq<<<4, 256, 0, stream>>>(KQf, KQP);
    build_G<<<64, 64, 0, stream>>>(embed_w, w_ih, b_ih, G4);
    compute_kv<<<(B_*M_)/4, 256, 0, stream>>>(memory, bqv, val_b, KQP, VWP,
                                              kqv, c0p, kT2, vT2, cB);
    recurrent_main<<<B_, 64, SMEM_BYTES, stream>>>(seq, b_hh, head_w, head_b,
                                                   kT2, vT2, G4, WPhh2, WR2p, cB,
                                                   (float*)d_out);
}